// Round 8
// baseline (99.298 us; speedup 1.0000x reference)
//
#include <hip/hip_runtime.h>
#include <hip/hip_bf16.h>
#include <math.h>

#define T_TOKENS 16384
#define DDIM 2048
#define NEXP 64
#define REFINE_TAU 4e-3f
#define KSPLIT 8
#define KPW (DDIM / KSPLIT)       // 256 k per wave
#define NCHW (KPW / 32)           // 8 chunks of 32-k per wave
#define BLK_TOK 16
#define NBLK (T_TOKENS / BLK_TOK) // 1024 blocks

typedef short bf16x8 __attribute__((ext_vector_type(8)));
typedef float f32x4 __attribute__((ext_vector_type(4)));

__device__ __forceinline__ short bf16hi(float f) {
    __hip_bfloat16 h = __float2bfloat16(f);       // RNE
    return *reinterpret_cast<short*>(&h);
}
__device__ __forceinline__ float bf16up(short s) {
    __hip_bfloat16 h = *reinterpret_cast<__hip_bfloat16*>(&s);
    return __bfloat162float(h);
}

// ---------------- Kernel 0: W -> fragment-ordered panels (hi/lo) ----------------
// Element (expert r, k) -> panel[((g*(DDIM/32) + ks)*64 + lane)*8 + j] with
// g=r>>4, ks=k>>5, lane=((k>>3)&3)*16 + (r&15), j=k&7.  (R4-R7-verified mapping.)
__global__ __launch_bounds__(256)
void prep_w(const float* __restrict__ W, short* __restrict__ ph, short* __restrict__ pl) {
    const int t  = blockIdx.x * 256 + threadIdx.x;   // 0..16383
    const int r  = t >> 8;                           // expert row
    const int kc = (t & 255) * 8;
    const float* wp = &W[(size_t)r * DDIM + kc];
    const float4 a = *(const float4*)wp;
    const float4 b = *(const float4*)(wp + 4);
    const float f[8] = { a.x, a.y, a.z, a.w, b.x, b.y, b.z, b.w };
    bf16x8 h, l;
#pragma unroll
    for (int j = 0; j < 8; ++j) {
        const short hh = bf16hi(f[j]);
        h[j] = hh;
        l[j] = bf16hi(f[j] - bf16up(hh));
    }
    const int g = r >> 4, ks = kc >> 5;
    const int lane = (((kc >> 3) & 3) << 4) + (r & 15);
    const size_t idx = ((((size_t)g * (DDIM / 32) + ks) * 64) + lane) * 8;
    *(bf16x8*)&ph[idx] = h;
    *(bf16x8*)&pl[idx] = l;
}

// ---------------- Kernel 1: barrier-free gate GEMM + fused top-2 ----------------
__device__ __forceinline__ bool better(double va, int ia, double vb, int ib) {
    return (va > vb) || (va == vb && ia < ib);
}
__device__ __forceinline__ double dot_f64(const float* __restrict__ xrow,
                                          const float* __restrict__ wr, int lane) {
    double sd = 0.0;
    for (int d = lane; d < DDIM; d += 64)
        sd = fma((double)xrow[d], (double)wr[d], sd);
#pragma unroll
    for (int off = 32; off >= 1; off >>= 1) sd += __shfl_xor(sd, off);
    return sd;
}

#define LOADX(slot, c) do { \
    const float* p_ = xsrc + (size_t)(c) * 32; \
    xr[slot][0] = *(const float4*)p_; \
    xr[slot][1] = *(const float4*)(p_ + 4); \
} while (0)

#define LOADP(buf, c) do { \
    _Pragma("unroll") \
    for (int mt_ = 0; mt_ < 4; ++mt_) { \
        const size_t ib_ = pbase + (size_t)(c) * 512 + (size_t)mt_ * ((DDIM / 32) * 512); \
        pa[buf][mt_]     = *(const bf16x8*)&ph[ib_]; \
        pa[buf][4 + mt_] = *(const bf16x8*)&pl[ib_]; \
    } \
} while (0)

#define CHUNK(slot, buf) do { \
    const float f_[8] = { xr[slot][0].x, xr[slot][0].y, xr[slot][0].z, xr[slot][0].w, \
                          xr[slot][1].x, xr[slot][1].y, xr[slot][1].z, xr[slot][1].w }; \
    bf16x8 bh_, bl_; \
    _Pragma("unroll") \
    for (int j_ = 0; j_ < 8; ++j_) { \
        const short s_ = bf16hi(f_[j_]); \
        bh_[j_] = s_; \
        bl_[j_] = bf16hi(f_[j_] - bf16up(s_)); \
    } \
    _Pragma("unroll") \
    for (int mt_ = 0; mt_ < 4; ++mt_) { \
        acc[mt_] = __builtin_amdgcn_mfma_f32_16x16x32_bf16(pa[buf][mt_],     bh_, acc[mt_], 0, 0, 0); \
        acc[mt_] = __builtin_amdgcn_mfma_f32_16x16x32_bf16(pa[buf][4 + mt_], bh_, acc[mt_], 0, 0, 0); \
        acc[mt_] = __builtin_amdgcn_mfma_f32_16x16x32_bf16(pa[buf][mt_],     bl_, acc[mt_], 0, 0, 0); \
    } \
} while (0)

__global__ __launch_bounds__(512)
__attribute__((amdgpu_waves_per_eu(4, 4)))   // pin occupancy: 128-VGPR budget, scheduler keeps values live
void gate_fused(const float* __restrict__ x,
                const short* __restrict__ ph,
                const short* __restrict__ pl,
                const float* __restrict__ W,
                float* __restrict__ out) {
    __shared__ float part[KSPLIT][NEXP][17];   // 34.8 KB

    const int tid  = threadIdx.x;
    const int lane = tid & 63;
    const int w    = tid >> 6;                 // K-slice 0..7
    const int tokb = blockIdx.x * BLK_TOK;

    // x source: token tokb+(lane&15), k base = w*256 + (lane>>4)*8  (B-frag layout)
    const float* xsrc = x + (size_t)(tokb + (lane & 15)) * DDIM
                          + (size_t)w * KPW + ((lane >> 4) << 3);
    // panel base for this wave's K-slice (chunk stride 512 shorts, mt stride 32768)
    const size_t pbase = ((size_t)(w * NCHW) * 64 + (size_t)lane) * 8;

    f32x4 acc[4] = { {0,0,0,0}, {0,0,0,0}, {0,0,0,0}, {0,0,0,0} };
    float4 xr[2][2];
    bf16x8 pa[2][8];

    // prologue: 2-deep x prefetch, 1-deep panel prefetch
    LOADX(0, 0); LOADX(1, 1);
    LOADP(0, 0);

#pragma unroll
    for (int c = 0; c < NCHW; ++c) {
        if (c + 1 < NCHW) LOADP((c + 1) & 1, c + 1);
        CHUNK(c & 1, c & 1);
        if (c + 2 < NCHW) LOADX(c & 1, c + 2);
    }

    // ---- partials -> LDS (C layout: col=lane&15=token, row=(lane>>4)*4+j=expert-in-tile) ----
#pragma unroll
    for (int mt = 0; mt < 4; ++mt)
#pragma unroll
        for (int j = 0; j < 4; ++j) {
            const int e = mt * 16 + ((lane >> 4) << 2) + j;
            part[w][e][lane & 15] = acc[mt][j];
        }
    __syncthreads();

    // ---- epilogue: wave w owns 2 tokens; fixed-order K reduction (deterministic) ----
    float* __restrict__ outw = out;
    float* __restrict__ outi = out + (size_t)T_TOKENS * 2;

#pragma unroll 1
    for (int t = 0; t < 2; ++t) {
        const int lt  = w * 2 + t;
        const int tok = tokb + lt;
        const float l = (((part[0][lane][lt] + part[1][lane][lt])
                        + (part[2][lane][lt] + part[3][lane][lt]))
                       + ((part[4][lane][lt] + part[5][lane][lt])
                        + (part[6][lane][lt] + part[7][lane][lt])));

        float v1 = l; int i1 = lane;
#pragma unroll
        for (int off = 32; off >= 1; off >>= 1) {
            const float ov = __shfl_xor(v1, off);
            const int   oi = __shfl_xor(i1, off);
            if (ov > v1 || (ov == v1 && oi < i1)) { v1 = ov; i1 = oi; }
        }
        float v2 = (lane == i1) ? -INFINITY : l; int i2 = lane;
#pragma unroll
        for (int off = 32; off >= 1; off >>= 1) {
            const float ov = __shfl_xor(v2, off);
            const int   oi = __shfl_xor(i2, off);
            if (ov > v2 || (ov == v2 && oi < i2)) { v2 = ov; i2 = oi; }
        }
        float v3 = (lane == i1 || lane == i2) ? -INFINITY : l; int i3 = lane;
#pragma unroll
        for (int off = 32; off >= 1; off >>= 1) {
            const float ov = __shfl_xor(v3, off);
            const int   oi = __shfl_xor(i3, off);
            if (ov > v3 || (ov == v3 && oi < i3)) { v3 = ov; i3 = oi; }
        }

        const float p = expf(l - v1);
        float s = p;
#pragma unroll
        for (int off = 32; off >= 1; off >>= 1) s += __shfl_xor(s, off);

        int iA = i1, iB = i2;
        if ((v1 - v2) < REFINE_TAU || (v2 - v3) < REFINE_TAU) {
            const float* __restrict__ xrow = x + (size_t)tok * DDIM;
            double La = dot_f64(xrow, W + (size_t)i1 * DDIM, lane);
            double Lb = dot_f64(xrow, W + (size_t)i2 * DDIM, lane);
            double Lc = dot_f64(xrow, W + (size_t)i3 * DDIM, lane);
            int ia = i1, ib = i2, ic = i3;
            if (!better(La, ia, Lb, ib)) { double tv = La; La = Lb; Lb = tv; int ti = ia; ia = ib; ib = ti; }
            if (!better(Lb, ib, Lc, ic)) { double tv = Lb; Lb = Lc; Lc = tv; int ti = ib; ib = ic; ic = ti; }
            if (!better(La, ia, Lb, ib)) { double tv = La; La = Lb; Lb = tv; int ti = ia; ia = ib; ib = ti; }
            iA = ia; iB = ib;
        }

        const float pA = __shfl(p, iA);
        const float pB = __shfl(p, iB);
        const float pa_ = pA / s;
        const float pb_ = pB / s;
        const float inv = 1.0f / (pa_ + pb_ + 1e-9f);

        if (lane == 0) {
            const size_t tg2 = (size_t)tok;
            outw[tg2 * 2]     = pa_ * inv;
            outw[tg2 * 2 + 1] = pb_ * inv;
            outi[tg2 * 2]     = (float)iA;
            outi[tg2 * 2 + 1] = (float)iB;
        }
    }
}

extern "C" void kernel_launch(void* const* d_in, const int* in_sizes, int n_in,
                              void* d_out, int out_size, void* d_ws, size_t ws_size,
                              hipStream_t stream) {
    const float* x = (const float*)d_in[0];
    const float* W = (const float*)d_in[1];
    float* out = (float*)d_out;

    short* ph = (short*)d_ws;                          // 256 KB hi panel
    short* pl = ph + (size_t)NEXP * DDIM;              // 256 KB lo panel

    prep_w<<<NEXP * DDIM / 8 / 256, 256, 0, stream>>>(W, ph, pl);
    gate_fused<<<NBLK, 512, 0, stream>>>(x, ph, pl, W, out);
}